// Round 7
// baseline (166.418 us; speedup 1.0000x reference)
//
#include <hip/hip_runtime.h>
#include <hip/hip_bf16.h>
#include <stdint.h>

// Problem: B=4, S=1024, D=1024, H=16, HS=64. fp32 inputs/outputs, bf16 MFMA.
#define NEG_SENTINEL (-1e30f)

typedef short s16x8 __attribute__((ext_vector_type(8)));
typedef float f32x4 __attribute__((ext_vector_type(4)));
typedef float f32x16 __attribute__((ext_vector_type(16)));
typedef unsigned int uint32x2 __attribute__((ext_vector_type(2)));

__device__ __forceinline__ ushort f2bf(float f) {  // RTNE
  union { float f; uint32_t u; } v; v.f = f;
  uint32_t u = v.u;
  u += 0x7fffu + ((u >> 16) & 1u);
  return (ushort)(u >> 16);
}
__device__ __forceinline__ ushort f2bf_rn(float f) {  // round-nearest (cheap)
  union { float f; uint32_t u; } v; v.f = f;
  return (ushort)((v.u + 0x8000u) >> 16);
}

__device__ __forceinline__ uint32_t pk_bf16(float lo, float hi) {
  uint32_t r;
  asm("v_cvt_pk_bf16_f32 %0, %1, %2" : "=v"(r) : "v"(lo), "v"(hi));
  return r;
}

// async global->LDS, 16 B per lane. LDS dest: wave-uniform base + lane*16.
__device__ __forceinline__ void async_ld16(ushort* lds, const ushort* g) {
  __builtin_amdgcn_global_load_lds(
      (const __attribute__((address_space(1))) uint32_t*)g,
      (__attribute__((address_space(3))) uint32_t*)lds, 16, 0, 0);
}

// ---------------------------------------------------------------------------
// Merged preprocessing: ONE launch, 1D grid of 3072 blocks x 256 thr.
//   g <  2048 : data fp32 -> bf16 bulk convert (8 elems/thread)
//   g <  2816 : Wq/Wk/Wv transpose+convert  (768 units: z = u>>4, it = u&15)
//   g >= 2816 : Wo transpose+convert        (256 units: jt = u&15, it = u>>4)
// ---------------------------------------------------------------------------
__global__ __launch_bounds__(256) void prep_all(
    const float* __restrict__ data, const float* __restrict__ Wq,
    const float* __restrict__ Wk, const float* __restrict__ Wv,
    const float* __restrict__ Wo, ushort* __restrict__ dataB,
    ushort* __restrict__ WTall, ushort* __restrict__ WoT) {
  const int g = blockIdx.x;
  const int tid = threadIdx.x;
  __shared__ __align__(16) ushort tile[64 * 72];

  if (g < 2048) {  // ---- bulk convert
    long i = ((long)g * 256 + tid) * 8;
    float4 a = *(const float4*)(data + i);
    float4 b = *(const float4*)(data + i + 4);
    union { ushort u[8]; uint4 v; } o;
    o.u[0] = f2bf(a.x); o.u[1] = f2bf(a.y); o.u[2] = f2bf(a.z); o.u[3] = f2bf(a.w);
    o.u[4] = f2bf(b.x); o.u[5] = f2bf(b.y); o.u[6] = f2bf(b.z); o.u[7] = f2bf(b.w);
    *(uint4*)(dataB + i) = o.v;
    return;
  }

  if (g < 2816) {  // ---- Wq/Wk/Wv transpose: [1024][64] -> [64][1024]
    const int u = g - 2048;
    const int z = u >> 4, it = u & 15;
    const int matsel = z >> 4;
    const float* src = (matsel == 0 ? Wq : (matsel == 1 ? Wk : Wv)) +
                       (long)(z & 15) * 65536;
    ushort* dst = WTall + (long)z * 65536;
#pragma unroll
    for (int p = 0; p < 4; ++p) {
      int chunk = tid + p * 256;
      int r = chunk >> 4, c0 = (chunk & 15) * 4;
      float4 f = *(const float4*)(src + (long)(it * 64 + r) * 64 + c0);
      union { ushort u2[4]; uint2 v; } o;
      o.u2[0] = f2bf(f.x); o.u2[1] = f2bf(f.y);
      o.u2[2] = f2bf(f.z); o.u2[3] = f2bf(f.w);
      *(uint2*)&tile[r * 72 + c0] = o.v;
    }
    __syncthreads();
#pragma unroll
    for (int p = 0; p < 2; ++p) {
      int chunk = tid + p * 256;
      int r = chunk >> 3, c0 = (chunk & 7) * 8;
      union { ushort u2[8]; uint4 v; } tmp;
#pragma unroll
      for (int k2 = 0; k2 < 8; ++k2) tmp.u2[k2] = tile[(c0 + k2) * 72 + r];
      *(uint4*)(dst + (long)r * 1024 + it * 64 + c0) = tmp.v;
    }
    return;
  }

  // ---- Wo transpose: [1024][1024] -> [n][k]
  {
    const int u = g - 2816;
    const int jt = u & 15, it = u >> 4;
#pragma unroll
    for (int p = 0; p < 4; ++p) {
      int chunk = tid + p * 256;
      int r = chunk >> 4, c0 = (chunk & 15) * 4;
      float4 f = *(const float4*)(Wo + (long)(it * 64 + r) * 1024 + jt * 64 + c0);
      union { ushort u2[4]; uint2 v; } o;
      o.u2[0] = f2bf(f.x); o.u2[1] = f2bf(f.y);
      o.u2[2] = f2bf(f.z); o.u2[3] = f2bf(f.w);
      *(uint2*)&tile[r * 72 + c0] = o.v;
    }
    __syncthreads();
#pragma unroll
    for (int p = 0; p < 2; ++p) {
      int chunk = tid + p * 256;
      int r = chunk >> 3, c0 = (chunk & 7) * 8;
      union { ushort u2[8]; uint4 v; } tmp;
#pragma unroll
      for (int k2 = 0; k2 < 8; ++k2) tmp.u2[k2] = tile[(c0 + k2) * 72 + r];
      *(uint4*)(WoT + (long)(jt * 64 + r) * 1024 + it * 64 + c0) = tmp.v;
    }
  }
}

// ---------------------------------------------------------------------------
// Fused QKV projection, 256x256-tile 8-phase schedule (T2+T3+T4+T5).
// grid (16, 12) with XCD-aware bijective remap (192 = 8 x 24 chunks).
// 512 threads (8 waves, 2M x 4N). BK=64, K=1024 -> 16 K-tiles, 8 iterations
// of 2 tiles. LDS 128 KiB: 2 buf x (A 256x64 + B 256x64) bf16, st_16x32 XOR
// swizzle via linear gload_lds dest + inverse-swizzled SOURCE + swizzled
// ds_read. Counted vmcnt(4) only at phases 4/8.
// __launch_bounds__(512, 1): min-waves=2 would cap VGPR at 128 -> spill.
// Q pre-scaled by log2(e)/sqrt(D) (softmax later uses exp2 directly).
// Q/K/V written in FRAGMENT-PACKED layouts (see attn_kernel):
//   QP/KP elem (s,e): (s>>5)*2048 + (e>>4)*512 + ((e>>3)&1)*256 + (s&31)*8 + (e&7)
//   VP    elem (s,e): (s>>5)*2048 + ((e>>5)+2*((s>>4)&1))*512
//                     + ((e&31)+32*((s>>3)&1))*8 + (s&7)
// ---------------------------------------------------------------------------
#define BAR() do { asm volatile("" ::: "memory"); \
  __builtin_amdgcn_s_barrier(); \
  asm volatile("" ::: "memory"); } while (0)
#define LGKM0() do { asm volatile("s_waitcnt lgkmcnt(0)" ::: "memory"); \
  __builtin_amdgcn_sched_barrier(0); } while (0)
#define STAGE2(LDSB, G) do { \
  async_ld16((LDSB) + o0, (G) + so0); \
  async_ld16((LDSB) + o0 + 4096, (G) + so0 + 65536); } while (0)
#define LD_A(PA, MIB) do { \
  _Pragma("unroll") for (int dm = 0; dm < 4; ++dm) { \
    afr[dm][0] = *(const s16x8*)((PA) + ((MIB) + dm) * 1024); \
    afr[dm][1] = *(const s16x8*)((PA) + ((MIB) + dm) * 1024 + 512); } } while (0)
#define LD_B(PB, NIB) do { \
  _Pragma("unroll") for (int dn = 0; dn < 2; ++dn) { \
    bfr[(NIB) + dn][0] = *(const s16x8*)((PB) + ((NIB) + dn) * 1024); \
    bfr[(NIB) + dn][1] = *(const s16x8*)((PB) + ((NIB) + dn) * 1024 + 512); } } while (0)
#define MFMA_Q(MIB, NIB) do { \
  __builtin_amdgcn_s_setprio(1); \
  _Pragma("unroll") for (int kg = 0; kg < 2; ++kg) \
    _Pragma("unroll") for (int dm = 0; dm < 4; ++dm) \
      _Pragma("unroll") for (int dn = 0; dn < 2; ++dn) \
        acc[(MIB) + dm][(NIB) + dn] = __builtin_amdgcn_mfma_f32_16x16x32_bf16( \
            afr[dm][kg], bfr[(NIB) + dn][kg], acc[(MIB) + dm][(NIB) + dn], 0, 0, 0); \
  __builtin_amdgcn_s_setprio(0); } while (0)

__global__ __launch_bounds__(512, 1) void qkv_proj256(
    const ushort* __restrict__ dataB, const ushort* __restrict__ WTall,
    ushort* __restrict__ QKV) {
  __shared__ __align__(16) ushort smem[65536];  // 128 KiB
  const int tid = threadIdx.x;
  const int lane = tid & 63, w = tid >> 6, quad = lane >> 4, l15 = lane & 15;
  const int wm = w >> 2, wn = w & 3;
  // XCD-aware bijective remap (T1): blocks with bid%8==xcd get a contiguous
  // 24-tile chunk -> per-XCD L2 panel reuse. 192 % 8 == 0 -> bijective.
  const int bid = blockIdx.x + (blockIdx.y << 4);
  const int wg = (bid & 7) * 24 + (bid >> 3);
  const int m0 = (wg & 15) * 256;
  const int n0 = (wg >> 4) * 256;

  // Staging geometry: LDS dest is linear (chunk*4096 + tid*8 ushorts);
  // invert the st_16x32 swizzle on the SOURCE address (involution).
  const int o0 = tid * 8;
  const int st_ = o0 >> 9, u_ = o0 & 511;
  const int u0_ = u_ ^ (((u_ >> 8) & 1) << 4);
  const long so0 = (long)((st_ >> 1) * 16 + (u0_ >> 5)) * 1024 +
                   (st_ & 1) * 32 + (u0_ & 31);

  const ushort* Ab = dataB + (long)m0 * 1024;
  const ushort* Bb = WTall + (long)n0 * 1024;

  // Swizzled per-lane ds_read base: within-subtile (sr*32+sc) ^ ((sr>>3)<<4).
  const int alane = (l15 * 32 + quad * 8) ^ (((l15 >> 3) & 1) << 4);
  const ushort* pA0 = smem + wm * 8192 + alane;
  const ushort* pB0 = smem + 16384 + (wn >> 1) * 8192 + (wn & 1) * 4096 + alane;
  const ushort* pA1 = pA0 + 32768;
  const ushort* pB1 = pB0 + 32768;

  f32x4 acc[8][4];
  const f32x4 z = {0.f, 0.f, 0.f, 0.f};
#pragma unroll
  for (int mi = 0; mi < 8; ++mi)
#pragma unroll
    for (int ni = 0; ni < 4; ++ni) acc[mi][ni] = z;

  s16x8 afr[4][2];
  s16x8 bfr[4][2];

  // Prologue: tile0 -> buf0 (all 4 halves), tile1 B-halves -> buf1.
  STAGE2(smem + 16384, Bb);
  STAGE2(smem + 16384 + 8192, Bb + 131072);
  STAGE2(smem, Ab);
  STAGE2(smem + 8192, Ab + 131072);
  STAGE2(smem + 32768 + 16384, Bb + 64);
  STAGE2(smem + 32768 + 16384 + 8192, Bb + 131072 + 64);
  asm volatile("s_waitcnt vmcnt(4)" ::: "memory");
  BAR();

#pragma unroll 1
  for (int it = 0; it < 8; ++it) {
    const int t0k = it * 128;        // k-offset of tile t0 = 2*it
    const bool sN = (it < 7);
    // ---- ph1: compute buf0 Q(mi0-3,ni0-1); stage buf1 A-half0 (tile t1)
    LD_A(pA0, 0); LD_B(pB0, 0);
    STAGE2(smem + 32768, Ab + t0k + 64);
    asm volatile("s_waitcnt lgkmcnt(8)" ::: "memory");
    BAR(); LGKM0();
    MFMA_Q(0, 0);
    BAR();
    // ---- ph2: Q(mi0-3,ni2-3); stage buf1 A-half1 (t1)
    LD_B(pB0, 2);
    STAGE2(smem + 32768 + 8192, Ab + 131072 + t0k + 64);
    BAR(); LGKM0();
    MFMA_Q(0, 2);
    BAR();
    // ---- ph3: Q(mi4-7,ni0-1); stage buf0 B-half0 (t0+2)
    LD_A(pA0, 4);
    if (sN) STAGE2(smem + 16384, Bb + t0k + 128);
    BAR(); LGKM0();
    MFMA_Q(4, 0);
    BAR();
    // ---- ph4: Q(mi4-7,ni2-3); stage buf0 B-half1 (t0+2); counted wait
    if (sN) STAGE2(smem + 16384 + 8192, Bb + 131072 + t0k + 128);
    BAR(); LGKM0();
    MFMA_Q(4, 2);
    if (sN) { asm volatile("s_waitcnt vmcnt(4)" ::: "memory"); }
    else    { asm volatile("s_waitcnt vmcnt(0)" ::: "memory"); }
    BAR();
    // ---- ph5: compute buf1 (tile t1) Q(mi0-3,ni0-1); stage buf0 A-half0 (t0+2)
    LD_A(pA1, 0); LD_B(pB1, 0);
    if (sN) STAGE2(smem, Ab + t0k + 128);
    asm volatile("s_waitcnt lgkmcnt(8)" ::: "memory");
    BAR(); LGKM0();
    MFMA_Q(0, 0);
    BAR();
    // ---- ph6: Q(mi0-3,ni2-3); stage buf0 A-half1 (t0+2)
    LD_B(pB1, 2);
    if (sN) STAGE2(smem + 8192, Ab + 131072 + t0k + 128);
    BAR(); LGKM0();
    MFMA_Q(0, 2);
    BAR();
    // ---- ph7: Q(mi4-7,ni0-1); stage buf1 B-half0 (t1+2)
    LD_A(pA1, 4);
    if (sN) STAGE2(smem + 32768 + 16384, Bb + t0k + 192);
    BAR(); LGKM0();
    MFMA_Q(4, 0);
    BAR();
    // ---- ph8: Q(mi4-7,ni2-3); stage buf1 B-half1 (t1+2); counted wait
    if (sN) STAGE2(smem + 32768 + 16384 + 8192, Bb + 131072 + t0k + 192);
    BAR(); LGKM0();
    MFMA_Q(4, 2);
    if (sN) {
      asm volatile("s_waitcnt vmcnt(4)" ::: "memory");
      BAR();
    }
  }

  // Epilogue: write fragment-packed per-head layouts.
  const int matsel = n0 >> 10;
  const int bI = m0 >> 10, s0 = m0 & 1023;
  const int nloc0 = (n0 & 1023) + wn * 64;
  if (matsel < 2) {
    // Q scale = log2(e)/sqrt(1024) so attention uses exp2 directly.
    const float sc = (matsel == 0) ? 0.04508422f : 1.0f;
    ushort* base = QKV + (long)matsel * 4194304 + (long)bI * 1048576;
#pragma unroll
    for (int mi = 0; mi < 8; ++mi) {
#pragma unroll
      for (int ni = 0; ni < 4; ++ni) {
        int n = nloc0 + ni * 16 + l15;
        int h = n >> 6, e = n & 63;
        int sb = s0 + wm * 128 + mi * 16 + quad * 4;
        ushort* p = base + (long)h * 65536 + (sb >> 5) * 2048 + (e >> 4) * 512 +
                    ((e >> 3) & 1) * 256 + (sb & 31) * 8 + (e & 7);
#pragma unroll
        for (int i = 0; i < 4; ++i)
          p[i * 8] = f2bf(acc[mi][ni][i] * sc);
      }
    }
  } else {
    // VP: 4 consecutive s at fixed e -> contiguous 8B store (j = sb&7 .. +3).
    ushort* base = QKV + 8388608 + (long)bI * 1048576;
#pragma unroll
    for (int mi = 0; mi < 8; ++mi) {
#pragma unroll
      for (int ni = 0; ni < 4; ++ni) {
        int n = nloc0 + ni * 16 + l15;
        int h = n >> 6, e = n & 63;
        int sb = s0 + wm * 128 + mi * 16 + quad * 4;
        union { ushort u[4]; uint2 v; } o;
#pragma unroll
        for (int i = 0; i < 4; ++i) o.u[i] = f2bf(acc[mi][ni][i]);
        *(uint2*)(base + (long)h * 65536 + (sb >> 5) * 2048 +
                  ((e >> 5) + 2 * ((sb >> 4) & 1)) * 512 +
                  ((e & 31) + 32 * ((sb >> 3) & 1)) * 8 + (sb & 7)) = o.v;
      }
    }
  }
}

// ---------------------------------------------------------------------------
// Output projection: 128x128 tile, 512 threads (8 waves 2M x 4N), st_16x32
// swizzle (same verified algebra as qkv), and a 3-BUFFER 2-DEEP counted-vmcnt
// pipeline (T3+T4): stage tile t+2 while computing tile t; end-of-iter wait
// is vmcnt(4) (t+1's 4 loads complete; t+2's stay in flight). Hazards:
//  - b[(t+2)%3] == b[(t-1)%3]: overwrite issued after the barrier closing
//    iter t-1's reads (reads consumed by its MFMAs before that barrier).
//  - tile t's loads: drained by vmcnt(4) at end of iter t-1.
// LDS 96 KiB (3 x 32 KiB) -> still 1 block/CU (grid 256 = CU count).
// XCD-aware bijective remap (256 = 8 x 32 chunks). grid (32, 8).
// ---------------------------------------------------------------------------
__global__ __launch_bounds__(512, 1) void out_proj(
    const ushort* __restrict__ Ocat, const ushort* __restrict__ WoT,
    const float* __restrict__ bo, float* __restrict__ out) {
  __shared__ __align__(16) ushort As[3][8192];
  __shared__ __align__(16) ushort Bs[3][8192];
  const int tid = threadIdx.x;
  const int lane = tid & 63, w = tid >> 6, quad = lane >> 4, l15 = lane & 15;
  const int wm = w >> 2, wn = w & 3;   // wave tile: rows wm*64, cols wn*32
  const int bid = blockIdx.x + (blockIdx.y << 5);
  const int wg = (bid & 7) * 32 + (bid >> 3);
  const int m0 = (wg & 31) * 128;
  const int n0 = (wg >> 5) * 128;
  const ushort* A = Ocat + (long)m0 * 1024;
  const ushort* BT = WoT + (long)n0 * 1024;

  // Inverse-swizzled source offset for linear LDS dest o0 (o0+4096 is +64
  // global rows = +65536 elems, same verified algebra as qkv).
  const int o0 = tid * 8;
  const int st_ = o0 >> 9, u_ = o0 & 511;
  const int u0_ = u_ ^ (((u_ >> 8) & 1) << 4);
  const long so0 = (long)((st_ >> 1) * 16 + (u0_ >> 5)) * 1024 +
                   (st_ & 1) * 32 + (u0_ & 31);

  // Swizzled ds_read base.
  const int alane = (l15 * 32 + quad * 8) ^ (((l15 >> 3) & 1) << 4);

  f32x4 acc[4][2];
  const f32x4 z = {0.f, 0.f, 0.f, 0.f};
#pragma unroll
  for (int mi = 0; mi < 4; ++mi)
#pragma unroll
    for (int ni = 0; ni < 2; ++ni) acc[mi][ni] = z;

#define OP_STAGE(BUF, K0) do { \
  async_ld16(&As[BUF][o0], A + (K0) + so0); \
  async_ld16(&As[BUF][o0 + 4096], A + (K0) + so0 + 65536); \
  async_ld16(&Bs[BUF][o0], BT + (K0) + so0); \
  async_ld16(&Bs[BUF][o0 + 4096], BT + (K0) + so0 + 65536); } while (0)

  // Prologue: stage tiles 0 and 1; wait for tile 0 (4 newest stay in flight).
  OP_STAGE(0, 0);
  OP_STAGE(1, 64);
  asm volatile("s_waitcnt vmcnt(4)" ::: "memory");
  BAR();

  int cur = 0;
#pragma unroll 1
  for (int t = 0; t < 16; ++t) {
    if (t < 14) {
      const int nxt = (cur + 2 >= 3) ? cur - 1 : cur + 2;
      OP_STAGE(nxt, (t + 2) * 64);
    }
    const ushort* pA = &As[cur][alane];
    const ushort* pB = &Bs[cur][alane];
#pragma unroll
    for (int kg = 0; kg < 2; ++kg) {
      s16x8 af[4], bfr[2];
#pragma unroll
      for (int mi = 0; mi < 4; ++mi)
        af[mi] = *(const s16x8*)(pA + (wm * 8 + mi * 2 + kg) * 512);
#pragma unroll
      for (int ni = 0; ni < 2; ++ni)
        bfr[ni] = *(const s16x8*)(pB + (wn * 4 + ni * 2 + kg) * 512);
#pragma unroll
      for (int mi = 0; mi < 4; ++mi)
#pragma unroll
        for (int ni = 0; ni < 2; ++ni)
          acc[mi][ni] = __builtin_amdgcn_mfma_f32_16x16x32_bf16(
              af[mi], bfr[ni], acc[mi][ni], 0, 0, 0);
    }
    if (t < 14)      { asm volatile("s_waitcnt vmcnt(4)" ::: "memory"); }
    else if (t == 14){ asm volatile("s_waitcnt vmcnt(0)" ::: "memory"); }
    if (t < 15) BAR();
    cur = (cur + 1 >= 3) ? 0 : cur + 1;
  }
#undef OP_STAGE

#pragma unroll
  for (int mi = 0; mi < 4; ++mi) {
#pragma unroll
    for (int ni = 0; ni < 2; ++ni) {
#pragma unroll
      for (int i = 0; i < 4; ++i) {
        int m = m0 + wm * 64 + mi * 16 + quad * 4 + i;
        int n = n0 + wn * 32 + ni * 16 + l15;
        out[(long)m * 1024 + n] = acc[mi][ni][i] + bo[n];
      }
    }
  }
}

// ---------------------------------------------------------------------------
// Causal flash attention, REGISTER-RESIDENT (no LDS, no barriers).
// Swapped QK^T via mfma_32x32x16 (m214/T12 structure): each lane's col = one
// q-row, so P lives in registers; softmax is lane-local + one shfl_xor(32).
// Q/K/V are FRAGMENT-PACKED by qkv_proj256 -> every operand load is 64
// lanes x 16B fully contiguous. C->A redistribution via v_permlane32_swap
// (T12). T5 setprio wraps MFMA clusters.
// 512-thread blocks: waves 0-3 heavy (c=31-(x>>4)), waves 4-7 light (c=x>>4)
// -> per-SIMD (s, s+4) pairing guarantees heavy+light per SIMD.
// ---------------------------------------------------------------------------
#define LOAD_KV(KF, VF, S) do { \
  _Pragma("unroll") for (int es = 0; es < 4; ++es) \
    KF[es] = *(const s16x8*)(Kp + (S) * 2048 + es * 512 + lane * 8); \
  _Pragma("unroll") for (int t = 0; t < 4; ++t) \
    VF[t] = *(const s16x8*)(VTp + (S) * 2048 + t * 512 + lane * 8); } while (0)

#define ATTN_STEP(KF, VF, S) do { \
  f32x16 sacc; \
  _Pragma("unroll") for (int r = 0; r < 16; ++r) sacc[r] = 0.f; \
  __builtin_amdgcn_s_setprio(1); \
  _Pragma("unroll") for (int es = 0; es < 4; ++es) \
    sacc = __builtin_amdgcn_mfma_f32_32x32x16_bf16(KF[es], qf[es], sacc, 0, 0, 0); \
  __builtin_amdgcn_s_setprio(0); \
  if ((S) == c) { \
    _Pragma("unroll") for (int r = 0; r < 16; ++r) { \
      int kvoff = (r & 3) + 8 * (r >> 2) + 4 * hi; \
      if (kvoff > l31) sacc[r] = NEG_SENTINEL; \
    } \
  } \
  float ex[16]; \
  _Pragma("unroll") for (int r = 0; r < 16; ++r) { \
    ex[r] = exp2f(sacc[r]); l_part += ex[r]; } \
  uint32_t xw[8]; \
  _Pragma("unroll") for (int k = 0; k < 8; ++k) \
    xw[k] = pk_bf16(ex[2 * k], ex[2 * k + 1]); \
  _Pragma("unroll") for (int win = 0; win < 2; ++win) { \
    const int bs = 4 * win; \
    uint32x2 sw0 = __builtin_amdgcn_permlane32_swap(xw[bs + 0], xw[bs + 2], \
                                                    false, false); \
    uint32x2 sw1 = __builtin_amdgcn_permlane32_swap(xw[bs + 1], xw[bs + 3], \
                                                    false, false); \
    union { uint32_t u[4]; s16x8 v; } pa; \
    pa.u[0] = sw0[0]; pa.u[1] = sw1[0]; pa.u[2] = sw0[1]; pa.u[3] = sw1[1]; \
    __builtin_amdgcn_s_setprio(1); \
    oacc0 = __builtin_amdgcn_mfma_f32_32x32x16_bf16(pa.v, VF[win * 2 + 0], \
                                                    oacc0, 0, 0, 0); \
    oacc1 = __builtin_amdgcn_mfma_f32_32x32x16_bf16(pa.v, VF[win * 2 + 1], \
                                                    oacc1, 0, 0, 0); \
    __builtin_amdgcn_s_setprio(0); \
  } } while (0)

__global__ __launch_bounds__(512, 1) void attn_kernel(
    const ushort* __restrict__ QKV, ushort* __restrict__ Ocat) {
  const int x = blockIdx.x;          // 0..255
  const int tid = threadIdx.x;
  const int w = tid >> 6;            // 0..7
  const int lane = tid & 63, l31 = lane & 31, hi = lane >> 5;
  const int c = (w < 4) ? (31 - (x >> 4)) : (x >> 4);
  const int bh = (x & 15) * 4 + (w & 3);
  const int b = bh >> 4, h = bh & 15;
  const int q0 = c * 32;

  const ushort* Qp = QKV + (long)bh * 65536;
  const ushort* Kp = QKV + 4194304 + (long)bh * 65536;
  const ushort* VTp = QKV + 8388608 + (long)bh * 65536;

  // Q fragments (persistent B-operand), packed: subtile c, slot es, lane.
  s16x8 qf[4];
#pragma unroll
  for (int es = 0; es < 4; ++es)
    qf[es] = *(const s16x8*)(Qp + c * 2048 + es * 512 + lane * 8);

  f32x16 oacc0, oacc1;  // O[q(reg)][e = l31 + 32*ncol]
#pragma unroll
  for (int r = 0; r < 16; ++r) { oacc0[r] = 0.f; oacc1[r] = 0.f; }
  float l_part = 0.f;
  const int nsub = c + 1;

  // Ping-pong K/V fragment buffers (no per-iter copies).
  s16x8 kc[4], vc[4], kn[4], vn[4];
  LOAD_KV(kc, vc, 0);

  int s = 0;
  while (true) {
    bool last = (s + 1 >= nsub);
    if (!last) LOAD_KV(kn, vn, s + 1);
    ATTN_STEP(kc, vc, s);
    if (last) break;
    ++s;
    last = (s + 1 >= nsub);
    if (!last) LOAD_KV(kc, vc, s + 1);
    ATTN_STEP(kn, vn, s);
    if (last) break;
    ++s;
  }

  // Row sums: partner halves hold complementary kv slices.
  float l_tot = l_part + __shfl_xor(l_part, 32, 64);

  ushort* Ob = Ocat + ((long)(b * 1024 + q0) * 1024) + h * 64;
#pragma unroll
  for (int r = 0; r < 16; ++r) {
    int qloc = (r & 3) + 8 * (r >> 2) + 4 * hi;
    float lv = __shfl(l_tot, qloc, 64);
    float linv = __builtin_amdgcn_rcpf(lv > 1e-30f ? lv : 1.0f);
    Ob[(long)qloc * 1024 + l31] = f2bf_rn(oacc0[r] * linv);
    Ob[(long)qloc * 1024 + 32 + l31] = f2bf_rn(oacc1[r] * linv);
  }
}

// ---------------------------------------------------------------------------
// Workspace (ushort elems), 24M = 48 MB:
//   [0)    QP 4M (pre-scaled, packed) | [4M) KP 4M (packed) | [8M) VP 4M
//   [12M)  dataB 4M | [16M) Ocat 4M | [20M) WTall 3M | [23M) WoT 1M
// ---------------------------------------------------------------------------
extern "C" void kernel_launch(void* const* d_in, const int* in_sizes, int n_in,
                              void* d_out, int out_size, void* d_ws, size_t ws_size,
                              hipStream_t stream) {
  const float* data = (const float*)d_in[0];
  const float* Wq = (const float*)d_in[1];
  const float* Wk = (const float*)d_in[2];
  const float* Wv = (const float*)d_in[3];
  const float* Wo = (const float*)d_in[4];
  const float* bo = (const float*)d_in[5];
  float* out = (float*)d_out;

  ushort* ws = (ushort*)d_ws;
  ushort* QKV = ws;                     // QP | KP | VP
  ushort* dataB = ws + 12582912;
  ushort* Ocat = ws + 16777216;
  ushort* WTall = ws + 20971520;
  ushort* WoT = ws + 20971520 + 3145728;

  prep_all<<<dim3(3072), dim3(256), 0, stream>>>(data, Wq, Wk, Wv, Wo,
                                                 dataB, WTall, WoT);
  qkv_proj256<<<dim3(16, 12), dim3(512), 0, stream>>>(dataB, WTall, QKV);
  attn_kernel<<<dim3(256), dim3(512), 0, stream>>>(QKV, Ocat);
  out_proj<<<dim3(32, 8), dim3(512), 0, stream>>>(Ocat, WoT, bo, out);
}

// Round 9
// 160.127 us; speedup vs baseline: 1.0393x; 1.0393x over previous
//
#include <hip/hip_runtime.h>
#include <hip/hip_bf16.h>
#include <stdint.h>

// Problem: B=4, S=1024, D=1024, H=16, HS=64. fp32 inputs/outputs, bf16 MFMA.
#define NEG_SENTINEL (-1e30f)

typedef short s16x8 __attribute__((ext_vector_type(8)));
typedef float f32x4 __attribute__((ext_vector_type(4)));
typedef float f32x16 __attribute__((ext_vector_type(16)));
typedef unsigned int uint32x2 __attribute__((ext_vector_type(2)));

__device__ __forceinline__ ushort f2bf(float f) {  // RTNE
  union { float f; uint32_t u; } v; v.f = f;
  uint32_t u = v.u;
  u += 0x7fffu + ((u >> 16) & 1u);
  return (ushort)(u >> 16);
}
__device__ __forceinline__ ushort f2bf_rn(float f) {  // round-nearest (cheap)
  union { float f; uint32_t u; } v; v.f = f;
  return (ushort)((v.u + 0x8000u) >> 16);
}

__device__ __forceinline__ uint32_t pk_bf16(float lo, float hi) {
  uint32_t r;
  asm("v_cvt_pk_bf16_f32 %0, %1, %2" : "=v"(r) : "v"(lo), "v"(hi));
  return r;
}

// async global->LDS, 16 B per lane. LDS dest: wave-uniform base + lane*16.
__device__ __forceinline__ void async_ld16(ushort* lds, const ushort* g) {
  __builtin_amdgcn_global_load_lds(
      (const __attribute__((address_space(1))) uint32_t*)g,
      (__attribute__((address_space(3))) uint32_t*)lds, 16, 0, 0);
}

// ---------------------------------------------------------------------------
// Merged preprocessing: ONE launch, 1D grid of 3072 blocks x 256 thr.
//   g <  2048 : data fp32 -> bf16 bulk convert (8 elems/thread)
//   g <  2816 : Wq/Wk/Wv transpose+convert  (768 units: z = u>>4, it = u&15)
//   g >= 2816 : Wo transpose+convert        (256 units: jt = u&15, it = u>>4)
// ---------------------------------------------------------------------------
__global__ __launch_bounds__(256) void prep_all(
    const float* __restrict__ data, const float* __restrict__ Wq,
    const float* __restrict__ Wk, const float* __restrict__ Wv,
    const float* __restrict__ Wo, ushort* __restrict__ dataB,
    ushort* __restrict__ WTall, ushort* __restrict__ WoT) {
  const int g = blockIdx.x;
  const int tid = threadIdx.x;
  __shared__ __align__(16) ushort tile[64 * 72];

  if (g < 2048) {  // ---- bulk convert
    long i = ((long)g * 256 + tid) * 8;
    float4 a = *(const float4*)(data + i);
    float4 b = *(const float4*)(data + i + 4);
    union { ushort u[8]; uint4 v; } o;
    o.u[0] = f2bf(a.x); o.u[1] = f2bf(a.y); o.u[2] = f2bf(a.z); o.u[3] = f2bf(a.w);
    o.u[4] = f2bf(b.x); o.u[5] = f2bf(b.y); o.u[6] = f2bf(b.z); o.u[7] = f2bf(b.w);
    *(uint4*)(dataB + i) = o.v;
    return;
  }

  if (g < 2816) {  // ---- Wq/Wk/Wv transpose: [1024][64] -> [64][1024]
    const int u = g - 2048;
    const int z = u >> 4, it = u & 15;
    const int matsel = z >> 4;
    const float* src = (matsel == 0 ? Wq : (matsel == 1 ? Wk : Wv)) +
                       (long)(z & 15) * 65536;
    ushort* dst = WTall + (long)z * 65536;
#pragma unroll
    for (int p = 0; p < 4; ++p) {
      int chunk = tid + p * 256;
      int r = chunk >> 4, c0 = (chunk & 15) * 4;
      float4 f = *(const float4*)(src + (long)(it * 64 + r) * 64 + c0);
      union { ushort u2[4]; uint2 v; } o;
      o.u2[0] = f2bf(f.x); o.u2[1] = f2bf(f.y);
      o.u2[2] = f2bf(f.z); o.u2[3] = f2bf(f.w);
      *(uint2*)&tile[r * 72 + c0] = o.v;
    }
    __syncthreads();
#pragma unroll
    for (int p = 0; p < 2; ++p) {
      int chunk = tid + p * 256;
      int r = chunk >> 3, c0 = (chunk & 7) * 8;
      union { ushort u2[8]; uint4 v; } tmp;
#pragma unroll
      for (int k2 = 0; k2 < 8; ++k2) tmp.u2[k2] = tile[(c0 + k2) * 72 + r];
      *(uint4*)(dst + (long)r * 1024 + it * 64 + c0) = tmp.v;
    }
    return;
  }

  // ---- Wo transpose: [1024][1024] -> [n][k]
  {
    const int u = g - 2816;
    const int jt = u & 15, it = u >> 4;
#pragma unroll
    for (int p = 0; p < 4; ++p) {
      int chunk = tid + p * 256;
      int r = chunk >> 4, c0 = (chunk & 15) * 4;
      float4 f = *(const float4*)(Wo + (long)(it * 64 + r) * 1024 + jt * 64 + c0);
      union { ushort u2[4]; uint2 v; } o;
      o.u2[0] = f2bf(f.x); o.u2[1] = f2bf(f.y);
      o.u2[2] = f2bf(f.z); o.u2[3] = f2bf(f.w);
      *(uint2*)&tile[r * 72 + c0] = o.v;
    }
    __syncthreads();
#pragma unroll
    for (int p = 0; p < 2; ++p) {
      int chunk = tid + p * 256;
      int r = chunk >> 3, c0 = (chunk & 7) * 8;
      union { ushort u2[8]; uint4 v; } tmp;
#pragma unroll
      for (int k2 = 0; k2 < 8; ++k2) tmp.u2[k2] = tile[(c0 + k2) * 72 + r];
      *(uint4*)(WoT + (long)(jt * 64 + r) * 1024 + it * 64 + c0) = tmp.v;
    }
  }
}

// ---------------------------------------------------------------------------
// Fused QKV projection, 256x256-tile 8-phase schedule (T2+T3+T4+T5).
// grid (16, 12), 512 threads (8 waves, 2M x 4N). BK=64, K=1024 -> 16 K-tiles,
// 8 iterations of 2 tiles. LDS 128 KiB: 2 buf x (A 256x64 + B 256x64) bf16,
// st_16x32 XOR swizzle via linear gload_lds dest + inverse-swizzled SOURCE +
// swizzled ds_read. Counted vmcnt(4) only at phases 4/8.
// __launch_bounds__(512, 1): min-waves=2 would cap VGPR at 128 -> spill.
// NO XCD swizzle: operands are L3-fit; T1 costs ~2% in that regime (R7 A/B).
// Q pre-scaled by log2(e)/sqrt(D) (softmax later uses exp2 directly).
// Q/K/V written in FRAGMENT-PACKED layouts (see attn_kernel):
//   QP/KP elem (s,e): (s>>5)*2048 + (e>>4)*512 + ((e>>3)&1)*256 + (s&31)*8 + (e&7)
//   VP    elem (s,e): (s>>5)*2048 + ((e>>5)+2*((s>>4)&1))*512
//                     + ((e&31)+32*((s>>3)&1))*8 + (s&7)
// ---------------------------------------------------------------------------
#define BAR() do { asm volatile("" ::: "memory"); \
  __builtin_amdgcn_s_barrier(); \
  asm volatile("" ::: "memory"); } while (0)
#define LGKM0() do { asm volatile("s_waitcnt lgkmcnt(0)" ::: "memory"); \
  __builtin_amdgcn_sched_barrier(0); } while (0)
#define STAGE2(LDSB, G) do { \
  async_ld16((LDSB) + o0, (G) + so0); \
  async_ld16((LDSB) + o0 + 4096, (G) + so0 + 65536); } while (0)
#define LD_A(PA, MIB) do { \
  _Pragma("unroll") for (int dm = 0; dm < 4; ++dm) { \
    afr[dm][0] = *(const s16x8*)((PA) + ((MIB) + dm) * 1024); \
    afr[dm][1] = *(const s16x8*)((PA) + ((MIB) + dm) * 1024 + 512); } } while (0)
#define LD_B(PB, NIB) do { \
  _Pragma("unroll") for (int dn = 0; dn < 2; ++dn) { \
    bfr[(NIB) + dn][0] = *(const s16x8*)((PB) + ((NIB) + dn) * 1024); \
    bfr[(NIB) + dn][1] = *(const s16x8*)((PB) + ((NIB) + dn) * 1024 + 512); } } while (0)
#define MFMA_Q(MIB, NIB) do { \
  __builtin_amdgcn_s_setprio(1); \
  _Pragma("unroll") for (int kg = 0; kg < 2; ++kg) \
    _Pragma("unroll") for (int dm = 0; dm < 4; ++dm) \
      _Pragma("unroll") for (int dn = 0; dn < 2; ++dn) \
        acc[(MIB) + dm][(NIB) + dn] = __builtin_amdgcn_mfma_f32_16x16x32_bf16( \
            afr[dm][kg], bfr[(NIB) + dn][kg], acc[(MIB) + dm][(NIB) + dn], 0, 0, 0); \
  __builtin_amdgcn_s_setprio(0); } while (0)

__global__ __launch_bounds__(512, 1) void qkv_proj256(
    const ushort* __restrict__ dataB, const ushort* __restrict__ WTall,
    ushort* __restrict__ QKV) {
  __shared__ __align__(16) ushort smem[65536];  // 128 KiB
  const int tid = threadIdx.x;
  const int lane = tid & 63, w = tid >> 6, quad = lane >> 4, l15 = lane & 15;
  const int wm = w >> 2, wn = w & 3;
  const int m0 = blockIdx.x * 256;
  const int n0 = blockIdx.y * 256;

  // Staging geometry: LDS dest is linear (chunk*4096 + tid*8 ushorts);
  // invert the st_16x32 swizzle on the SOURCE address (involution).
  const int o0 = tid * 8;
  const int st_ = o0 >> 9, u_ = o0 & 511;
  const int u0_ = u_ ^ (((u_ >> 8) & 1) << 4);
  const long so0 = (long)((st_ >> 1) * 16 + (u0_ >> 5)) * 1024 +
                   (st_ & 1) * 32 + (u0_ & 31);

  const ushort* Ab = dataB + (long)m0 * 1024;
  const ushort* Bb = WTall + (long)n0 * 1024;

  // Swizzled per-lane ds_read base: within-subtile (sr*32+sc) ^ ((sr>>3)<<4).
  const int alane = (l15 * 32 + quad * 8) ^ (((l15 >> 3) & 1) << 4);
  const ushort* pA0 = smem + wm * 8192 + alane;
  const ushort* pB0 = smem + 16384 + (wn >> 1) * 8192 + (wn & 1) * 4096 + alane;
  const ushort* pA1 = pA0 + 32768;
  const ushort* pB1 = pB0 + 32768;

  f32x4 acc[8][4];
  const f32x4 z = {0.f, 0.f, 0.f, 0.f};
#pragma unroll
  for (int mi = 0; mi < 8; ++mi)
#pragma unroll
    for (int ni = 0; ni < 4; ++ni) acc[mi][ni] = z;

  s16x8 afr[4][2];
  s16x8 bfr[4][2];

  // Prologue: tile0 -> buf0 (all 4 halves), tile1 B-halves -> buf1.
  STAGE2(smem + 16384, Bb);
  STAGE2(smem + 16384 + 8192, Bb + 131072);
  STAGE2(smem, Ab);
  STAGE2(smem + 8192, Ab + 131072);
  STAGE2(smem + 32768 + 16384, Bb + 64);
  STAGE2(smem + 32768 + 16384 + 8192, Bb + 131072 + 64);
  asm volatile("s_waitcnt vmcnt(4)" ::: "memory");
  BAR();

#pragma unroll 1
  for (int it = 0; it < 8; ++it) {
    const int t0k = it * 128;        // k-offset of tile t0 = 2*it
    const bool sN = (it < 7);
    // ---- ph1: compute buf0 Q(mi0-3,ni0-1); stage buf1 A-half0 (tile t1)
    LD_A(pA0, 0); LD_B(pB0, 0);
    STAGE2(smem + 32768, Ab + t0k + 64);
    asm volatile("s_waitcnt lgkmcnt(8)" ::: "memory");
    BAR(); LGKM0();
    MFMA_Q(0, 0);
    BAR();
    // ---- ph2: Q(mi0-3,ni2-3); stage buf1 A-half1 (t1)
    LD_B(pB0, 2);
    STAGE2(smem + 32768 + 8192, Ab + 131072 + t0k + 64);
    BAR(); LGKM0();
    MFMA_Q(0, 2);
    BAR();
    // ---- ph3: Q(mi4-7,ni0-1); stage buf0 B-half0 (t0+2)
    LD_A(pA0, 4);
    if (sN) STAGE2(smem + 16384, Bb + t0k + 128);
    BAR(); LGKM0();
    MFMA_Q(4, 0);
    BAR();
    // ---- ph4: Q(mi4-7,ni2-3); stage buf0 B-half1 (t0+2); counted wait
    if (sN) STAGE2(smem + 16384 + 8192, Bb + 131072 + t0k + 128);
    BAR(); LGKM0();
    MFMA_Q(4, 2);
    if (sN) { asm volatile("s_waitcnt vmcnt(4)" ::: "memory"); }
    else    { asm volatile("s_waitcnt vmcnt(0)" ::: "memory"); }
    BAR();
    // ---- ph5: compute buf1 (tile t1) Q(mi0-3,ni0-1); stage buf0 A-half0 (t0+2)
    LD_A(pA1, 0); LD_B(pB1, 0);
    if (sN) STAGE2(smem, Ab + t0k + 128);
    asm volatile("s_waitcnt lgkmcnt(8)" ::: "memory");
    BAR(); LGKM0();
    MFMA_Q(0, 0);
    BAR();
    // ---- ph6: Q(mi0-3,ni2-3); stage buf0 A-half1 (t0+2)
    LD_B(pB1, 2);
    if (sN) STAGE2(smem + 8192, Ab + 131072 + t0k + 128);
    BAR(); LGKM0();
    MFMA_Q(0, 2);
    BAR();
    // ---- ph7: Q(mi4-7,ni0-1); stage buf1 B-half0 (t1+2)
    LD_A(pA1, 4);
    if (sN) STAGE2(smem + 32768 + 16384, Bb + t0k + 192);
    BAR(); LGKM0();
    MFMA_Q(4, 0);
    BAR();
    // ---- ph8: Q(mi4-7,ni2-3); stage buf1 B-half1 (t1+2); counted wait
    if (sN) STAGE2(smem + 32768 + 16384 + 8192, Bb + 131072 + t0k + 192);
    BAR(); LGKM0();
    MFMA_Q(4, 2);
    if (sN) {
      asm volatile("s_waitcnt vmcnt(4)" ::: "memory");
      BAR();
    }
  }

  // Epilogue: write fragment-packed per-head layouts.
  const int matsel = n0 >> 10;
  const int bI = m0 >> 10, s0 = m0 & 1023;
  const int nloc0 = (n0 & 1023) + wn * 64;
  if (matsel < 2) {
    // Q scale = log2(e)/sqrt(1024) so attention uses exp2 directly.
    const float sc = (matsel == 0) ? 0.04508422f : 1.0f;
    ushort* base = QKV + (long)matsel * 4194304 + (long)bI * 1048576;
#pragma unroll
    for (int mi = 0; mi < 8; ++mi) {
#pragma unroll
      for (int ni = 0; ni < 4; ++ni) {
        int n = nloc0 + ni * 16 + l15;
        int h = n >> 6, e = n & 63;
        int sb = s0 + wm * 128 + mi * 16 + quad * 4;
        ushort* p = base + (long)h * 65536 + (sb >> 5) * 2048 + (e >> 4) * 512 +
                    ((e >> 3) & 1) * 256 + (sb & 31) * 8 + (e & 7);
#pragma unroll
        for (int i = 0; i < 4; ++i)
          p[i * 8] = f2bf(acc[mi][ni][i] * sc);
      }
    }
  } else {
    // VP: 4 consecutive s at fixed e -> contiguous 8B store (j = sb&7 .. +3).
    ushort* base = QKV + 8388608 + (long)bI * 1048576;
#pragma unroll
    for (int mi = 0; mi < 8; ++mi) {
#pragma unroll
      for (int ni = 0; ni < 4; ++ni) {
        int n = nloc0 + ni * 16 + l15;
        int h = n >> 6, e = n & 63;
        int sb = s0 + wm * 128 + mi * 16 + quad * 4;
        union { ushort u[4]; uint2 v; } o;
#pragma unroll
        for (int i = 0; i < 4; ++i) o.u[i] = f2bf(acc[mi][ni][i]);
        *(uint2*)(base + (long)h * 65536 + (sb >> 5) * 2048 +
                  ((e >> 5) + 2 * ((sb >> 4) & 1)) * 512 +
                  ((e & 31) + 32 * ((sb >> 3) & 1)) * 8 + (sb & 7)) = o.v;
      }
    }
  }
}

// ---------------------------------------------------------------------------
// Output projection: 128x128 tile, 512 threads (8 waves 2M x 4N -> 2
// waves/SIMD for latency overlap), LDS double-buffer, st_16x32 swizzle
// (same verified algebra as qkv_proj256). R7's 3-buffer counted-vmcnt
// variant REGRESSED (coarse phase-split without fine interleave, m196) --
// this is the R6 known-good double-buffer. grid (32, 8).
// ---------------------------------------------------------------------------
__global__ __launch_bounds__(512, 1) void out_proj(
    const ushort* __restrict__ Ocat, const ushort* __restrict__ WoT,
    const float* __restrict__ bo, float* __restrict__ out) {
  __shared__ __align__(16) ushort As[2][8192];
  __shared__ __align__(16) ushort Bs[2][8192];
  const int m0 = blockIdx.x * 128;
  const int n0 = blockIdx.y * 128;
  const int tid = threadIdx.x;
  const int lane = tid & 63, w = tid >> 6, quad = lane >> 4, l15 = lane & 15;
  const int wm = w >> 2, wn = w & 3;   // wave tile: rows wm*64, cols wn*32
  const ushort* A = Ocat + (long)m0 * 1024;
  const ushort* BT = WoT + (long)n0 * 1024;

  // Inverse-swizzled source offset for linear LDS dest o0 (and o0+4096,
  // which is exactly +64 global rows = +65536, same as qkv geometry).
  const int o0 = tid * 8;
  const int st_ = o0 >> 9, u_ = o0 & 511;
  const int u0_ = u_ ^ (((u_ >> 8) & 1) << 4);
  const long so0 = (long)((st_ >> 1) * 16 + (u0_ >> 5)) * 1024 +
                   (st_ & 1) * 32 + (u0_ & 31);

  // Swizzled ds_read base; fragment (r = base_r + l15, c = kk + quad*8) is at
  // ((r>>4)*2 + (kk>>5))*512 + alane.
  const int alane = (l15 * 32 + quad * 8) ^ (((l15 >> 3) & 1) << 4);

  f32x4 acc[4][2];
  const f32x4 z = {0.f, 0.f, 0.f, 0.f};
#pragma unroll
  for (int mi = 0; mi < 4; ++mi)
#pragma unroll
    for (int ni = 0; ni < 2; ++ni) acc[mi][ni] = z;

  // Prologue: stage tile 0 -> buf 0.
  async_ld16(&As[0][o0], A + so0);
  async_ld16(&As[0][o0 + 4096], A + so0 + 65536);
  async_ld16(&Bs[0][o0], BT + so0);
  async_ld16(&Bs[0][o0 + 4096], BT + so0 + 65536);
  __syncthreads();

#pragma unroll 1
  for (int t = 0; t < 16; ++t) {
    const int cur = t & 1;
    if (t < 15) {
      const int k0 = (t + 1) * 64;
      async_ld16(&As[cur ^ 1][o0], A + k0 + so0);
      async_ld16(&As[cur ^ 1][o0 + 4096], A + k0 + so0 + 65536);
      async_ld16(&Bs[cur ^ 1][o0], BT + k0 + so0);
      async_ld16(&Bs[cur ^ 1][o0 + 4096], BT + k0 + so0 + 65536);
    }
    const ushort* pA = &As[cur][alane];
    const ushort* pB = &Bs[cur][alane];
#pragma unroll
    for (int kg = 0; kg < 2; ++kg) {
      s16x8 af[4], bfr[2];
#pragma unroll
      for (int mi = 0; mi < 4; ++mi)
        af[mi] = *(const s16x8*)(pA + (wm * 8 + mi * 2 + kg) * 512);
#pragma unroll
      for (int ni = 0; ni < 2; ++ni)
        bfr[ni] = *(const s16x8*)(pB + (wn * 4 + ni * 2 + kg) * 512);
#pragma unroll
      for (int mi = 0; mi < 4; ++mi)
#pragma unroll
        for (int ni = 0; ni < 2; ++ni)
          acc[mi][ni] = __builtin_amdgcn_mfma_f32_16x16x32_bf16(
              af[mi], bfr[ni], acc[mi][ni], 0, 0, 0);
    }
    __syncthreads();  // drains vmcnt(0): next buf staged; cur reads complete
  }

#pragma unroll
  for (int mi = 0; mi < 4; ++mi) {
#pragma unroll
    for (int ni = 0; ni < 2; ++ni) {
#pragma unroll
      for (int i = 0; i < 4; ++i) {
        int m = m0 + wm * 64 + mi * 16 + quad * 4 + i;
        int n = n0 + wn * 32 + ni * 16 + l15;
        out[(long)m * 1024 + n] = acc[mi][ni][i] + bo[n];
      }
    }
  }
}

// ---------------------------------------------------------------------------
// Causal flash attention, REGISTER-RESIDENT (no LDS, no barriers).
// Swapped QK^T via mfma_32x32x16 (m214/T12 structure): each lane's col = one
// q-row, so P lives in registers; softmax is lane-local + one shfl_xor(32).
// Q/K/V are FRAGMENT-PACKED by qkv_proj256 -> every operand load is 64
// lanes x 16B fully contiguous. C->A redistribution via v_permlane32_swap
// (T12). T5 setprio wraps MFMA clusters.
// 512-thread blocks: waves 0-3 heavy (c=31-(x>>4)), waves 4-7 light (c=x>>4)
// -> per-SIMD (s, s+4) pairing guarantees heavy+light per SIMD.
// ---------------------------------------------------------------------------
#define LOAD_KV(KF, VF, S) do { \
  _Pragma("unroll") for (int es = 0; es < 4; ++es) \
    KF[es] = *(const s16x8*)(Kp + (S) * 2048 + es * 512 + lane * 8); \
  _Pragma("unroll") for (int t = 0; t < 4; ++t) \
    VF[t] = *(const s16x8*)(VTp + (S) * 2048 + t * 512 + lane * 8); } while (0)

#define ATTN_STEP(KF, VF, S) do { \
  f32x16 sacc; \
  _Pragma("unroll") for (int r = 0; r < 16; ++r) sacc[r] = 0.f; \
  __builtin_amdgcn_s_setprio(1); \
  _Pragma("unroll") for (int es = 0; es < 4; ++es) \
    sacc = __builtin_amdgcn_mfma_f32_32x32x16_bf16(KF[es], qf[es], sacc, 0, 0, 0); \
  __builtin_amdgcn_s_setprio(0); \
  if ((S) == c) { \
    _Pragma("unroll") for (int r = 0; r < 16; ++r) { \
      int kvoff = (r & 3) + 8 * (r >> 2) + 4 * hi; \
      if (kvoff > l31) sacc[r] = NEG_SENTINEL; \
    } \
  } \
  float ex[16]; \
  _Pragma("unroll") for (int r = 0; r < 16; ++r) { \
    ex[r] = exp2f(sacc[r]); l_part += ex[r]; } \
  uint32_t xw[8]; \
  _Pragma("unroll") for (int k = 0; k < 8; ++k) \
    xw[k] = pk_bf16(ex[2 * k], ex[2 * k + 1]); \
  _Pragma("unroll") for (int win = 0; win < 2; ++win) { \
    const int bs = 4 * win; \
    uint32x2 sw0 = __builtin_amdgcn_permlane32_swap(xw[bs + 0], xw[bs + 2], \
                                                    false, false); \
    uint32x2 sw1 = __builtin_amdgcn_permlane32_swap(xw[bs + 1], xw[bs + 3], \
                                                    false, false); \
    union { uint32_t u[4]; s16x8 v; } pa; \
    pa.u[0] = sw0[0]; pa.u[1] = sw1[0]; pa.u[2] = sw0[1]; pa.u[3] = sw1[1]; \
    __builtin_amdgcn_s_setprio(1); \
    oacc0 = __builtin_amdgcn_mfma_f32_32x32x16_bf16(pa.v, VF[win * 2 + 0], \
                                                    oacc0, 0, 0, 0); \
    oacc1 = __builtin_amdgcn_mfma_f32_32x32x16_bf16(pa.v, VF[win * 2 + 1], \
                                                    oacc1, 0, 0, 0); \
    __builtin_amdgcn_s_setprio(0); \
  } } while (0)

__global__ __launch_bounds__(512, 1) void attn_kernel(
    const ushort* __restrict__ QKV, ushort* __restrict__ Ocat) {
  const int x = blockIdx.x;          // 0..255
  const int tid = threadIdx.x;
  const int w = tid >> 6;            // 0..7
  const int lane = tid & 63, l31 = lane & 31, hi = lane >> 5;
  const int c = (w < 4) ? (31 - (x >> 4)) : (x >> 4);
  const int bh = (x & 15) * 4 + (w & 3);
  const int b = bh >> 4, h = bh & 15;
  const int q0 = c * 32;

  const ushort* Qp = QKV + (long)bh * 65536;
  const ushort* Kp = QKV + 4194304 + (long)bh * 65536;
  const ushort* VTp = QKV + 8388608 + (long)bh * 65536;

  // Q fragments (persistent B-operand), packed: subtile c, slot es, lane.
  s16x8 qf[4];
#pragma unroll
  for (int es = 0; es < 4; ++es)
    qf[es] = *(const s16x8*)(Qp + c * 2048 + es * 512 + lane * 8);

  f32x16 oacc0, oacc1;  // O[q(reg)][e = l31 + 32*ncol]
#pragma unroll
  for (int r = 0; r < 16; ++r) { oacc0[r] = 0.f; oacc1[r] = 0.f; }
  float l_part = 0.f;
  const int nsub = c + 1;

  // Ping-pong K/V fragment buffers (no per-iter copies).
  s16x8 kc[4], vc[4], kn[4], vn[4];
  LOAD_KV(kc, vc, 0);

  int s = 0;
  while (true) {
    bool last = (s + 1 >= nsub);
    if (!last) LOAD_KV(kn, vn, s + 1);
    ATTN_STEP(kc, vc, s);
    if (last) break;
    ++s;
    last = (s + 1 >= nsub);
    if (!last) LOAD_KV(kc, vc, s + 1);
    ATTN_STEP(kn, vn, s);
    if (last) break;
    ++s;
  }

  // Row sums: partner halves hold complementary kv slices.
  float l_tot = l_part + __shfl_xor(l_part, 32, 64);

  ushort* Ob = Ocat + ((long)(b * 1024 + q0) * 1024) + h * 64;
#pragma unroll
  for (int r = 0; r < 16; ++r) {
    int qloc = (r & 3) + 8 * (r >> 2) + 4 * hi;
    float lv = __shfl(l_tot, qloc, 64);
    float linv = __builtin_amdgcn_rcpf(lv > 1e-30f ? lv : 1.0f);
    Ob[(long)qloc * 1024 + l31] = f2bf_rn(oacc0[r] * linv);
    Ob[(long)qloc * 1024 + 32 + l31] = f2bf_rn(oacc1[r] * linv);
  }
}

// ---------------------------------------------------------------------------
// Workspace (ushort elems), 24M = 48 MB:
//   [0)    QP 4M (pre-scaled, packed) | [4M) KP 4M (packed) | [8M) VP 4M
//   [12M)  dataB 4M | [16M) Ocat 4M | [20M) WTall 3M | [23M) WoT 1M
// ---------------------------------------------------------------------------
extern "C" void kernel_launch(void* const* d_in, const int* in_sizes, int n_in,
                              void* d_out, int out_size, void* d_ws, size_t ws_size,
                              hipStream_t stream) {
  const float* data = (const float*)d_in[0];
  const float* Wq = (const float*)d_in[1];
  const float* Wk = (const float*)d_in[2];
  const float* Wv = (const float*)d_in[3];
  const float* Wo = (const float*)d_in[4];
  const float* bo = (const float*)d_in[5];
  float* out = (float*)d_out;

  ushort* ws = (ushort*)d_ws;
  ushort* QKV = ws;                     // QP | KP | VP
  ushort* dataB = ws + 12582912;
  ushort* Ocat = ws + 16777216;
  ushort* WTall = ws + 20971520;
  ushort* WoT = ws + 20971520 + 3145728;

  prep_all<<<dim3(3072), dim3(256), 0, stream>>>(data, Wq, Wk, Wv, Wo,
                                                 dataB, WTall, WoT);
  qkv_proj256<<<dim3(16, 12), dim3(512), 0, stream>>>(dataB, WTall, QKV);
  attn_kernel<<<dim3(256), dim3(512), 0, stream>>>(QKV, Ocat);
  out_proj<<<dim3(32, 8), dim3(512), 0, stream>>>(Ocat, WoT, bo, out);
}